// Round 4
// baseline (1346.940 us; speedup 1.0000x reference)
//
#include <hip/hip_runtime.h>
#include <hip/hip_bf16.h>
#include <cstdint>
#include <type_traits>

#define DIM    4096
#define NHEADS 32
#define NKVH   8
#define HD     128
#define BATCH  2
#define SEQ    2048
#define MROWS  (BATCH*SEQ)      // 4096
#define NQKV   6144             // DIM + 2*NKVH*HD
#define KOFF   4096
#define VOFF   5120

typedef __attribute__((ext_vector_type(8))) __bf16 bf16x8;
typedef __attribute__((ext_vector_type(4))) __bf16 bf16x4;
typedef __attribute__((ext_vector_type(4))) float  f32x4;

// scale folded into Q: log2(e)/sqrt(HD) so softmax uses exp2 (native v_exp_f32)
#define QSCALE 0.1275174338f

__device__ __forceinline__ void gl_lds16(const __bf16* g, __bf16* l) {
    __builtin_amdgcn_global_load_lds(
        (const __attribute__((address_space(1))) void*)g,
        (__attribute__((address_space(3))) void*)l, 16, 0, 0);
}

// ---------------- fp32 -> bf16 cast (8 elem/thread) ----------------
__global__ void cast_f32_bf16(const float* __restrict__ s, __bf16* __restrict__ d, int n8) {
    int i = blockIdx.x * 256 + threadIdx.x;
    if (i >= n8) return;
    float4 a = ((const float4*)s)[2*i];
    float4 b = ((const float4*)s)[2*i+1];
    bf16x8 v;
    v[0]=(__bf16)a.x; v[1]=(__bf16)a.y; v[2]=(__bf16)a.z; v[3]=(__bf16)a.w;
    v[4]=(__bf16)b.x; v[5]=(__bf16)b.y; v[6]=(__bf16)b.z; v[7]=(__bf16)b.w;
    ((bf16x8*)d)[i] = v;
}

// ---------------- GEMM: C[m,n] = sum_k A[m,k]*B[n,k]  (both row-major, K contig) ----
// m97 structure + XOR-swizzled LDS (chunk ^= row&7). At the ~880 TF plateau.
template<typename OutT>
__global__ __launch_bounds__(256)
void gemm_bt(const __bf16* __restrict__ A, const __bf16* __restrict__ Bm,
             OutT* __restrict__ C, int M, int N, int K,
             float scale, int scale_cols)
{
    __shared__ __bf16 As[128*64];
    __shared__ __bf16 Bs[128*64];
    const int tid  = threadIdx.x;
    const int lane = tid & 63;
    const int w    = tid >> 6;
    const int quad = lane >> 4;
    const int l16  = lane & 15;
    const int m0   = blockIdx.y * 128;
    const int n0   = blockIdx.x * 128;
    const int wm   = (w & 1) * 64;
    const int wn   = (w >> 1) * 64;

    const __bf16* Ab = A  + (size_t)m0 * K;
    const __bf16* Bb = Bm + (size_t)n0 * K;

    f32x4 acc[4][4] = {};

    for (int k0 = 0; k0 < K; k0 += 64) {
        __syncthreads();
        #pragma unroll
        for (int r = 0; r < 4; ++r) {
            int chunk = r*256 + tid;
            int row = chunk >> 3, c8 = chunk & 7;
            int c8s = c8 ^ (row & 7);                 // source-side swizzle
            gl_lds16(Ab + (size_t)row*K + k0 + c8s*8, As + chunk*8);
            gl_lds16(Bb + (size_t)row*K + k0 + c8s*8, Bs + chunk*8);
        }
        __syncthreads();
        #pragma unroll
        for (int t = 0; t < 2; ++t) {                 // kk = t*32
            bf16x8 af[4], bfr[4];
            #pragma unroll
            for (int i = 0; i < 4; ++i) {
                int row = wm + i*16 + l16;
                int cc  = (t*4 + quad) ^ (row & 7);
                af[i] = *(const bf16x8*)(As + row*64 + cc*8);
            }
            #pragma unroll
            for (int j = 0; j < 4; ++j) {
                int row = wn + j*16 + l16;
                int cc  = (t*4 + quad) ^ (row & 7);
                bfr[j] = *(const bf16x8*)(Bs + row*64 + cc*8);
            }
            #pragma unroll
            for (int i = 0; i < 4; ++i)
                #pragma unroll
                for (int j = 0; j < 4; ++j)
                    acc[i][j] = __builtin_amdgcn_mfma_f32_16x16x32_bf16(af[i], bfr[j], acc[i][j], 0,0,0);
        }
    }

    // C/D layout: col = lane&15, row = quad*4 + reg  [verified m89/m91]
    #pragma unroll
    for (int i = 0; i < 4; ++i) {
        #pragma unroll
        for (int j = 0; j < 4; ++j) {
            int col = n0 + wn + j*16 + l16;
            float sc = (col < scale_cols) ? scale : 1.0f;
            #pragma unroll
            for (int r = 0; r < 4; ++r) {
                int row = m0 + wm + i*16 + quad*4 + r;
                float v = acc[i][j][r] * sc;
                if constexpr (std::is_same<OutT, float>::value)
                    C[(size_t)row * N + col] = v;
                else
                    C[(size_t)row * N + col] = (__bf16)v;
            }
        }
    }
}

// ---------------- V transpose: vt[(b*8+g)*128 + d][s] = qkv[b*T+s][VOFF + g*128 + d] ----
__global__ void transpose_v(const __bf16* __restrict__ qkv, __bf16* __restrict__ vt) {
    int idx  = blockIdx.x * 256 + threadIdx.x;  // 524288 total
    int s8   = idx & 255;                        // T/8
    int rest = idx >> 8;                         // (b*8+g)*128 + d
    int d    = rest & (HD-1);
    int bg   = rest >> 7;
    int b    = bg >> 3;
    int g    = bg & 7;
    int s0   = s8 * 8;
    const __bf16* src = qkv + (size_t)(b*SEQ + s0)*NQKV + VOFF + g*HD + d;
    bf16x8 v;
    #pragma unroll
    for (int u = 0; u < 8; ++u) v[u] = src[(size_t)u*NQKV];
    *(bf16x8*)(vt + (size_t)rest*SEQ + s0) = v;
}

// ---------------- flash attention: Q-tile 128 (two 64-row subtiles), K-tile 64 ----
// S^T formulation (lane owns a q-row). Both subtiles share one K/V staging:
// staging + barriers halved; PV bv reads shared by 2 MFMAs. Sub A skips its
// fully-masked final k-tile. LDS 48 KB -> 3 blocks/CU.
__global__ __launch_bounds__(256)
void flash_attn(const __bf16* __restrict__ qkv, const __bf16* __restrict__ vt,
                __bf16* __restrict__ O)
{
    __shared__ __bf16 Ks[64*128];   // [srow][d]   swizzled chunks
    __shared__ __bf16 Vts[128*64];  // [d][s]      swizzled chunks
    __shared__ __bf16 Ps[128*64];   // [qrow][s]   chunk-swizzled, per-wave rows

    const int qt = (gridDim.x - 1) - blockIdx.x;   // long blocks dispatch first
    const int bh = blockIdx.y;      // 0..63
    const int b  = bh >> 5;
    const int h  = bh & 31;
    const int g  = h >> 2;          // kv head (repeat_interleave)
    const int q0 = qt * 128;

    const int tid  = threadIdx.x;
    const int lane = tid & 63;
    const int w    = tid >> 6;
    const int quad = lane >> 4;
    const int l16  = lane & 15;
    const int psw  = (l16 & 7) << 1;   // Ps chunk swizzle (even -> keeps 16B pairs)

    const __bf16* QbA = qkv + (size_t)(b*SEQ + q0)*NQKV + h*HD;
    const __bf16* QbB = QbA + (size_t)64*NQKV;
    const __bf16* Kb  = qkv + (size_t)(b*SEQ)*NQKV + KOFF + g*HD;
    const __bf16* Vtb = vt  + (size_t)((b*NKVH + g)*HD)*SEQ;

    // Q fragments in registers (lane's q-row = w*16 + l16 within each subtile)
    bf16x8 qfA[4], qfB[4];
    #pragma unroll
    for (int t = 0; t < 4; ++t) {
        qfA[t] = *(const bf16x8*)(QbA + (size_t)(w*16 + l16)*NQKV + t*32 + quad*8);
        qfB[t] = *(const bf16x8*)(QbB + (size_t)(w*16 + l16)*NQKV + t*32 + quad*8);
    }

    f32x4 oA[8] = {}, oB[8] = {};
    float mA = -1e30f, lA = 0.f, mB = -1e30f, lB = 0.f;
    const int rowA = q0 + w*16 + l16;        // sub B row = rowA + 64
    const int rowB = rowA + 64;

    const int nkt = 2*qt + 2;
    for (int kt = 0; kt < nkt; ++kt) {
        const int s0 = kt * 64;
        __syncthreads();                   // prev-iter Ks/Vts reads done
        #pragma unroll
        for (int r = 0; r < 4; ++r) {
            int c = r*256 + tid;
            { int row = c >> 4, c16 = c & 15;
              int c16s = c16 ^ (row & 7);
              gl_lds16(Kb + (size_t)(s0 + row)*NQKV + c16s*8, Ks + c*8); }
            { int dd = c >> 3, c8 = c & 7;
              int c8s = c8 ^ (dd & 7);
              gl_lds16(Vtb + (size_t)dd*SEQ + s0 + c8s*8, Vts + c*8); }
        }
        __syncthreads();

        const bool actA = (kt <= 2*qt);    // last k-tile fully masks sub A

        // ---- sub A: S^T = K Q^T, softmax, Ps rows [0,64) ----
        if (actA) {
            f32x4 s_acc[4] = {};
            #pragma unroll
            for (int t = 0; t < 4; ++t)
                #pragma unroll
                for (int j = 0; j < 4; ++j) {
                    int row = j*16 + l16;
                    int cc  = (t*4 + quad) ^ (row & 7);
                    bf16x8 bk = *(const bf16x8*)(Ks + row*128 + cc*8);
                    s_acc[j] = __builtin_amdgcn_mfma_f32_16x16x32_bf16(bk, qfA[t], s_acc[j], 0,0,0);
                }
            if (kt == 2*qt) {
                #pragma unroll
                for (int j = 0; j < 4; ++j)
                    #pragma unroll
                    for (int r = 0; r < 4; ++r)
                        if (s0 + j*16 + quad*4 + r > rowA) s_acc[j][r] = -1e30f;
            }
            float pm = s_acc[0][0];
            #pragma unroll
            for (int j = 0; j < 4; ++j)
                #pragma unroll
                for (int r = 0; r < 4; ++r)
                    pm = fmaxf(pm, s_acc[j][r]);
            pm = fmaxf(pm, __shfl_xor(pm, 16));
            pm = fmaxf(pm, __shfl_xor(pm, 32));
            float mnew  = fmaxf(mA, pm);
            float alpha = exp2f(mA - mnew);
            mA = mnew;
            float psum = 0.f;
            #pragma unroll
            for (int j = 0; j < 4; ++j) {
                bf16x4 pv;
                #pragma unroll
                for (int r = 0; r < 4; ++r) {
                    float p = exp2f(s_acc[j][r] - mnew);
                    psum += p;
                    pv[r] = (__bf16)p;
                }
                int cs = (j*4 + quad) ^ psw;
                *(bf16x4*)(Ps + (w*16 + l16)*64 + cs*4) = pv;
            }
            psum += __shfl_xor(psum, 16);
            psum += __shfl_xor(psum, 32);
            lA = lA*alpha + psum;
            float av[4];
            #pragma unroll
            for (int r = 0; r < 4; ++r) av[r] = __shfl(alpha, quad*4 + r);
            #pragma unroll
            for (int jt = 0; jt < 8; ++jt)
                #pragma unroll
                for (int r = 0; r < 4; ++r)
                    oA[jt][r] *= av[r];
        }

        // ---- sub B: always active; Ps rows [64,128) ----
        {
            f32x4 s_acc[4] = {};
            #pragma unroll
            for (int t = 0; t < 4; ++t)
                #pragma unroll
                for (int j = 0; j < 4; ++j) {
                    int row = j*16 + l16;
                    int cc  = (t*4 + quad) ^ (row & 7);
                    bf16x8 bk = *(const bf16x8*)(Ks + row*128 + cc*8);
                    s_acc[j] = __builtin_amdgcn_mfma_f32_16x16x32_bf16(bk, qfB[t], s_acc[j], 0,0,0);
                }
            if (kt == 2*qt + 1) {
                #pragma unroll
                for (int j = 0; j < 4; ++j)
                    #pragma unroll
                    for (int r = 0; r < 4; ++r)
                        if (s0 + j*16 + quad*4 + r > rowB) s_acc[j][r] = -1e30f;
            }
            float pm = s_acc[0][0];
            #pragma unroll
            for (int j = 0; j < 4; ++j)
                #pragma unroll
                for (int r = 0; r < 4; ++r)
                    pm = fmaxf(pm, s_acc[j][r]);
            pm = fmaxf(pm, __shfl_xor(pm, 16));
            pm = fmaxf(pm, __shfl_xor(pm, 32));
            float mnew  = fmaxf(mB, pm);
            float alpha = exp2f(mB - mnew);
            mB = mnew;
            float psum = 0.f;
            #pragma unroll
            for (int j = 0; j < 4; ++j) {
                bf16x4 pv;
                #pragma unroll
                for (int r = 0; r < 4; ++r) {
                    float p = exp2f(s_acc[j][r] - mnew);
                    psum += p;
                    pv[r] = (__bf16)p;
                }
                int cs = (j*4 + quad) ^ psw;
                *(bf16x4*)(Ps + (64 + w*16 + l16)*64 + cs*4) = pv;
            }
            psum += __shfl_xor(psum, 16);
            psum += __shfl_xor(psum, 32);
            lB = lB*alpha + psum;
            float av[4];
            #pragma unroll
            for (int r = 0; r < 4; ++r) av[r] = __shfl(alpha, quad*4 + r);
            #pragma unroll
            for (int jt = 0; jt < 8; ++jt)
                #pragma unroll
                for (int r = 0; r < 4; ++r)
                    oB[jt][r] *= av[r];
        }

        // ---- PV: bv shared by both subtiles (Ps rows per-wave: lgkmcnt suffices) ----
        #pragma unroll
        for (int t = 0; t < 2; ++t) {
            int cs = (t*8 + quad*2) ^ psw;
            bf16x8 apB = *(const bf16x8*)(Ps + (64 + w*16 + l16)*64 + cs*4);
            bf16x8 apA;
            if (actA) apA = *(const bf16x8*)(Ps + (w*16 + l16)*64 + cs*4);
            #pragma unroll
            for (int jt = 0; jt < 8; ++jt) {
                int row = jt*16 + l16;
                int cc  = (t*4 + quad) ^ (row & 7);
                bf16x8 bv = *(const bf16x8*)(Vts + row*64 + cc*8);
                if (actA) oA[jt] = __builtin_amdgcn_mfma_f32_16x16x32_bf16(apA, bv, oA[jt], 0,0,0);
                oB[jt] = __builtin_amdgcn_mfma_f32_16x16x32_bf16(apB, bv, oB[jt], 0,0,0);
            }
        }
    }

    // epilogue: both subtiles
    {
        float inv = 1.0f / lA;
        float ivr[4];
        #pragma unroll
        for (int r = 0; r < 4; ++r) ivr[r] = __shfl(inv, quad*4 + r);
        #pragma unroll
        for (int jt = 0; jt < 8; ++jt)
            #pragma unroll
            for (int r = 0; r < 4; ++r) {
                int row = q0 + w*16 + quad*4 + r;
                int col = h*HD + jt*16 + l16;
                O[(size_t)(b*SEQ + row)*DIM + col] = (__bf16)(oA[jt][r] * ivr[r]);
            }
    }
    {
        float inv = 1.0f / lB;
        float ivr[4];
        #pragma unroll
        for (int r = 0; r < 4; ++r) ivr[r] = __shfl(inv, quad*4 + r);
        #pragma unroll
        for (int jt = 0; jt < 8; ++jt)
            #pragma unroll
            for (int r = 0; r < 4; ++r) {
                int row = q0 + 64 + w*16 + quad*4 + r;
                int col = h*HD + jt*16 + l16;
                O[(size_t)(b*SEQ + row)*DIM + col] = (__bf16)(oB[jt][r] * ivr[r]);
            }
    }
}

extern "C" void kernel_launch(void* const* d_in, const int* in_sizes, int n_in,
                              void* d_out, int out_size, void* d_ws, size_t ws_size,
                              hipStream_t stream) {
    const float* x   = (const float*)d_in[0];
    const float* Wq  = (const float*)d_in[1];
    const float* Wkv = (const float*)d_in[2];
    const float* Wo  = (const float*)d_in[3];

    // workspace layout (bytes)
    const size_t OFF_XB   = 0;                       // 4096*4096 bf16 = 32 MB
    const size_t OFF_WQKV = 33554432;                // 6144*4096 bf16 = 48 MB
    const size_t OFF_WO   = 83886080;                // 4096*4096 bf16 = 32 MB
    const size_t OFF_QKV  = 117440512;               // 4096*6144 bf16 = 48 MB
    const size_t OFF_VT   = 167772160;               // 2*8*128*2048 bf16 = 8 MB
    const size_t OFF_OB   = 176160768;               // 4096*4096 bf16 = 32 MB
    const size_t NEEDED   = 209715200;               // 200 MB
    if (ws_size < NEEDED) return;

    char* ws = (char*)d_ws;
    __bf16* xb   = (__bf16*)(ws + OFF_XB);
    __bf16* wqkv = (__bf16*)(ws + OFF_WQKV);
    __bf16* wo   = (__bf16*)(ws + OFF_WO);
    __bf16* qkv  = (__bf16*)(ws + OFF_QKV);
    __bf16* vt   = (__bf16*)(ws + OFF_VT);
    __bf16* ob   = (__bf16*)(ws + OFF_OB);

    cast_f32_bf16<<<16777216/8/256, 256, 0, stream>>>(x,   xb,              16777216/8);
    cast_f32_bf16<<<16777216/8/256, 256, 0, stream>>>(Wq,  wqkv,            16777216/8);
    cast_f32_bf16<<< 8388608/8/256, 256, 0, stream>>>(Wkv, wqkv + 16777216,  8388608/8);
    cast_f32_bf16<<<16777216/8/256, 256, 0, stream>>>(Wo,  wo,              16777216/8);

    gemm_bt<__bf16><<<dim3(NQKV/128, MROWS/128), 256, 0, stream>>>(
        xb, wqkv, qkv, MROWS, NQKV, DIM, QSCALE, DIM);

    transpose_v<<<524288/256, 256, 0, stream>>>(qkv, vt);

    flash_attn<<<dim3(SEQ/128, BATCH*NHEADS), 256, 0, stream>>>(qkv, vt, ob);

    gemm_bt<float><<<dim3(DIM/128, MROWS/128), 256, 0, stream>>>(
        ob, wo, (float*)d_out, MROWS, DIM, DIM, 1.0f, 0);
}